// Round 2
// baseline (2042.257 us; speedup 1.0000x reference)
//
#include <hip/hip_runtime.h>

#define SEQ 640
#define BATCH 40
#define D_IN 8
#define D_TRAJ 32
#define D_LSTM 64
#define G4 256        // 4 * D_LSTM
#define NH 4
#define DH 48
#define EMB 192

typedef float v2f __attribute__((ext_vector_type(2)));
typedef float v4f __attribute__((ext_vector_type(4)));

__device__ __forceinline__ float sigmoid_f(float x) {
    return 1.f / (1.f + __expf(-x));
}
__device__ __forceinline__ float tanh_f(float x) {
    // robust: 1 - 2/(e^{2x}+1); handles +-inf of __expf
    float e = __expf(2.f * x);
    return 1.f - 2.f / (e + 1.f);
}

// ---------------------------------------------------------------------------
// Kernel 1: trajectory embed (ELU) + input-side LSTM gate precompute.
// Writes gates_x in layout [b][t][j][g] (g in {i,f,g,o} fastest) so that
// k_lstm lane j reads its 4 gates with ONE global_load_dwordx4.
// grid: 640 blocks (t), 256 threads
// ---------------------------------------------------------------------------
__global__ void __launch_bounds__(256) k_embed(
    const float* __restrict__ hist, const float* __restrict__ W1,
    const float* __restrict__ b1, const float* __restrict__ W_ih,
    const float* __restrict__ b_ih, const float* __restrict__ b_hh,
    float* __restrict__ gates_x)
{
    __shared__ float sh_hist[BATCH * D_IN];     // 320
    __shared__ float sh_traj[BATCH * D_TRAJ];   // 1280
    const int t = blockIdx.x, tid = threadIdx.x;

    for (int i = tid; i < BATCH * D_IN; i += 256)
        sh_hist[i] = hist[t * BATCH * D_IN + i];
    __syncthreads();

    for (int idx = tid; idx < BATCH * D_TRAJ; idx += 256) {
        int b = idx >> 5, h = idx & 31;
        float acc = b1[h];
        #pragma unroll
        for (int f = 0; f < D_IN; ++f)
            acc += sh_hist[b * D_IN + f] * W1[h * D_IN + f];
        sh_traj[idx] = acc > 0.f ? acc : (__expf(acc) - 1.f);   // ELU
    }
    __syncthreads();

    // one gate row per thread (torch order rows [i;f;g;o]), loop over batch
    float w[D_TRAJ];
    #pragma unroll
    for (int h = 0; h < D_TRAJ; ++h) w[h] = W_ih[tid * D_TRAJ + h];
    const float bias = b_ih[tid] + b_hh[tid];
    const int j = tid & 63, g = tid >> 6;       // unit, gate-type

    for (int b = 0; b < BATCH; ++b) {
        float acc = bias;
        #pragma unroll
        for (int h = 0; h < D_TRAJ; ++h)
            acc += sh_traj[b * D_TRAJ + h] * w[h];
        gates_x[((size_t)b * SEQ + t) * G4 + j * 4 + g] = acc;
    }
}

// ---------------------------------------------------------------------------
// Kernel 2: LSTM recurrence — ONE WAVE per chain, zero barriers, zero LDS.
// Lane j owns unit j: c, h, and all 4 W_hh rows interleaved as float2 pairs
// so the matvec runs as v_pk_fma_f32 with __shfl(h,k) splat broadcasts.
// All 4 gates accumulate in-lane -> activations need no exchange.
// grid: 40 blocks x 64 threads.
// ---------------------------------------------------------------------------
__global__ void __launch_bounds__(64, 1) k_lstm(
    const float* __restrict__ gates_x, const float* __restrict__ W_hh,
    float* __restrict__ seq_out)
{
    const int b = blockIdx.x, j = threadIdx.x;

    // interleaved weights: wif[k] = (W_i[j][k], W_f[j][k]), wgo likewise
    v2f wif[D_LSTM], wgo[D_LSTM];
    const float* Wi = W_hh + (0 * 64 + j) * D_LSTM;
    const float* Wf = W_hh + (1 * 64 + j) * D_LSTM;
    const float* Wg = W_hh + (2 * 64 + j) * D_LSTM;
    const float* Wo = W_hh + (3 * 64 + j) * D_LSTM;
    #pragma unroll
    for (int k = 0; k < D_LSTM; ++k) {
        wif[k] = (v2f){Wi[k], Wf[k]};
        wgo[k] = (v2f){Wg[k], Wo[k]};
    }

    const v4f* gxp = (const v4f*)(gates_x + (size_t)b * SEQ * G4);
    v4f gx_cur = gxp[0 * 64 + j];
    v4f gx_nxt = gxp[1 * 64 + j];

    float h = 0.f, c = 0.f;

    for (int t = 0; t < SEQ; ++t) {
        v4f g4 = gx_cur;
        gx_cur = gx_nxt;
        int tp = (t + 2 < SEQ) ? t + 2 : SEQ - 1;
        gx_nxt = gxp[tp * 64 + j];             // distance-2 prefetch, no barrier

        v2f aif = (v2f){g4.x, g4.y};
        v2f ago = (v2f){g4.z, g4.w};
        #pragma unroll
        for (int k = 0; k < D_LSTM; ++k) {
            float hk = __shfl(h, k, 64);
            v2f hk2 = (v2f){hk, hk};
            aif += wif[k] * hk2;               // -> v_pk_fma_f32 (fp-contract)
            ago += wgo[k] * hk2;
        }

        float gi = aif.x, gf = aif.y, gg = ago.x, go = ago.y;
        c = sigmoid_f(gf) * c + sigmoid_f(gi) * tanh_f(gg);
        h = sigmoid_f(go) * tanh_f(c);
        seq_out[(size_t)(t * BATCH + b) * D_LSTM + j] = h;   // never drained by barrier
    }
}

// ---------------------------------------------------------------------------
// Kernel 3: multi-head attention over the 40-agent axis, per (head, t).
// grid: dim3(4, 640), 256 threads. Writes per-head o slice to ws.
// ---------------------------------------------------------------------------
#define SQK 49   // padded row stride for q/k/v in LDS (break 48-stride conflicts)
__global__ void __launch_bounds__(256) k_attn(
    const float* __restrict__ seq,
    const float* __restrict__ Wq, const float* __restrict__ bq,
    const float* __restrict__ Wk, const float* __restrict__ bk,
    const float* __restrict__ Wv, const float* __restrict__ bv,
    float* __restrict__ o_buf)
{
    const int h = blockIdx.x, t = blockIdx.y, tid = threadIdx.x;
    __shared__ float sseq[BATCH * D_LSTM];   // 2560
    __shared__ float sq[BATCH * SQK];        // 1960
    __shared__ float sk[BATCH * SQK];
    __shared__ float sv[BATCH * SQK];
    __shared__ float ss[BATCH * 41];         // scores, padded

    for (int i = tid; i < BATCH * D_LSTM; i += 256)
        sseq[i] = seq[t * BATCH * D_LSTM + i];
    __syncthreads();

    // q/k/v head slices: 3 * 1920 outputs, each a 64-dot
    for (int m = 0; m < 3; ++m) {
        const float* W    = (m == 0) ? Wq : (m == 1) ? Wk : Wv;
        const float* bias = (m == 0) ? bq : (m == 1) ? bk : bv;
        float* dst        = (m == 0) ? sq : (m == 1) ? sk : sv;
        for (int r = tid; r < BATCH * DH; r += 256) {
            int bi = r / DH, d = r % DH;
            int e = h * DH + d;
            const float* wrow = W + e * D_LSTM;
            const float* srow = sseq + bi * D_LSTM;
            float acc = bias[e];
            #pragma unroll 16
            for (int k = 0; k < D_LSTM; ++k) acc += srow[k] * wrow[k];
            dst[bi * SQK + d] = acc;
        }
    }
    __syncthreads();

    // scores = q k^T / 8
    for (int idx = tid; idx < BATCH * BATCH; idx += 256) {
        int i = idx / BATCH, j = idx % BATCH;
        float acc = 0.f;
        #pragma unroll 12
        for (int d = 0; d < DH; ++d) acc += sq[i * SQK + d] * sk[j * SQK + d];
        ss[i * 41 + j] = acc * 0.125f;
    }
    __syncthreads();

    // row softmax (one thread per row)
    if (tid < BATCH) {
        float m = -1e30f;
        for (int j = 0; j < BATCH; ++j) m = fmaxf(m, ss[tid * 41 + j]);
        float s = 0.f;
        for (int j = 0; j < BATCH; ++j) {
            float e = __expf(ss[tid * 41 + j] - m);
            ss[tid * 41 + j] = e;
            s += e;
        }
        float inv = 1.f / s;
        for (int j = 0; j < BATCH; ++j) ss[tid * 41 + j] *= inv;
    }
    __syncthreads();

    // o_h = a @ v ; write head slice into o_buf[t][b][h*48+d]
    for (int r = tid; r < BATCH * DH; r += 256) {
        int bi = r / DH, d = r % DH;
        float acc = 0.f;
        #pragma unroll 10
        for (int j = 0; j < BATCH; ++j) acc += ss[bi * 41 + j] * sv[j * SQK + d];
        o_buf[(t * BATCH + bi) * EMB + h * DH + d] = acc;
    }
}

// ---------------------------------------------------------------------------
// Kernel 4: GLU + residual + LayerNorm, per t. 256 threads.
// GLU phase: j = tid>>2 (output channel), bq = tid&3 (batch group of 10).
// LN phase: wave w handles rows {w, w+4, ...}; 64-lane shuffle reduction.
// ---------------------------------------------------------------------------
__global__ void __launch_bounds__(256) k_glu_ln(
    const float* __restrict__ seq, const float* __restrict__ obuf,
    const float* __restrict__ Wa, const float* __restrict__ ba,
    const float* __restrict__ Wg, const float* __restrict__ bg,
    const float* __restrict__ gamma, const float* __restrict__ beta,
    float* __restrict__ out)
{
    const int t = blockIdx.x, tid = threadIdx.x;
    __shared__ float so[BATCH * 193];       // o_t padded (192 -> 193)
    __shared__ float sy[BATCH * 65];        // y padded
    __shared__ float sseq[BATCH * D_LSTM];

    const float* ot = obuf + t * BATCH * EMB;
    for (int i = tid; i < BATCH * EMB; i += 256)
        so[(i / EMB) * 193 + (i % EMB)] = ot[i];
    for (int i = tid; i < BATCH * D_LSTM; i += 256)
        sseq[i] = seq[t * BATCH * D_LSTM + i];
    __syncthreads();

    const int j = tid >> 2, bgr = tid & 3;
    float acc_a[10], acc_g[10];
    #pragma unroll
    for (int bb = 0; bb < 10; ++bb) { acc_a[bb] = ba[j]; acc_g[bb] = bg[j]; }

    const float* wa = Wa + j * EMB;
    const float* wg = Wg + j * EMB;
    for (int p = 0; p < EMB; ++p) {
        float a = wa[p], g = wg[p];
        #pragma unroll
        for (int bb = 0; bb < 10; ++bb) {
            float o = so[(bgr + 4 * bb) * 193 + p];
            acc_a[bb] += o * a;
            acc_g[bb] += o * g;
        }
    }
    #pragma unroll
    for (int bb = 0; bb < 10; ++bb) {
        int b = bgr + 4 * bb;
        float tv = acc_a[bb] * sigmoid_f(acc_g[bb]);
        sy[b * 65 + j] = sseq[b * D_LSTM + j] + tv;
    }
    __syncthreads();

    const int w = tid >> 6, lane = tid & 63;
    const float gm = gamma[lane], bt = beta[lane];
    for (int rr = 0; rr < 10; ++rr) {
        int b = w + 4 * rr;
        float y = sy[b * 65 + lane];
        float s1 = y, s2 = y * y;
        #pragma unroll
        for (int m = 1; m < 64; m <<= 1) {
            s1 += __shfl_xor(s1, m, 64);
            s2 += __shfl_xor(s2, m, 64);
        }
        float mu  = s1 * (1.f / 64.f);
        float var = s2 * (1.f / 64.f) - mu * mu;
        float inv = rsqrtf(var + 1e-5f);
        out[t * BATCH * D_LSTM + b * D_LSTM + lane] = (y - mu) * inv * gm + bt;
    }
}

// ---------------------------------------------------------------------------
extern "C" void kernel_launch(void* const* d_in, const int* in_sizes, int n_in,
                              void* d_out, int out_size, void* d_ws, size_t ws_size,
                              hipStream_t stream)
{
    const float* hist = (const float*)d_in[0];
    // d_in[1] adj: unused (use_spatial=False)
    const float* W1   = (const float*)d_in[2];
    const float* b1   = (const float*)d_in[3];
    const float* W_ih = (const float*)d_in[4];
    const float* W_hh = (const float*)d_in[5];
    const float* b_ih = (const float*)d_in[6];
    const float* b_hh = (const float*)d_in[7];
    const float* Wq   = (const float*)d_in[8];
    const float* bq   = (const float*)d_in[9];
    const float* Wk   = (const float*)d_in[10];
    const float* bk   = (const float*)d_in[11];
    const float* Wv   = (const float*)d_in[12];
    const float* bv   = (const float*)d_in[13];
    const float* Wa   = (const float*)d_in[14];
    const float* ba   = (const float*)d_in[15];
    const float* Wg   = (const float*)d_in[16];
    const float* bg   = (const float*)d_in[17];
    const float* gamma = (const float*)d_in[18];
    const float* beta  = (const float*)d_in[19];
    float* out = (float*)d_out;

    float* ws = (float*)d_ws;
    float* gates_x = ws;                                   // 640*40*256 = 6,553,600 f
    float* seq     = ws + 6553600;                         // 640*40*64  = 1,638,400 f
    float* obuf    = ws + 6553600 + 1638400;               // 640*40*192 = 4,915,200 f

    hipLaunchKernelGGL(k_embed, dim3(SEQ), dim3(256), 0, stream,
                       hist, W1, b1, W_ih, b_ih, b_hh, gates_x);
    hipLaunchKernelGGL(k_lstm, dim3(BATCH), dim3(64), 0, stream,
                       gates_x, W_hh, seq);
    hipLaunchKernelGGL(k_attn, dim3(NH, SEQ), dim3(256), 0, stream,
                       seq, Wq, bq, Wk, bk, Wv, bv, obuf);
    hipLaunchKernelGGL(k_glu_ln, dim3(SEQ), dim3(256), 0, stream,
                       seq, obuf, Wa, ba, Wg, bg, gamma, beta, out);
}

// Round 4
// 1115.515 us; speedup vs baseline: 1.8308x; 1.8308x over previous
//
#include <hip/hip_runtime.h>

#define SEQ 640
#define BATCH 40
#define D_IN 8
#define D_TRAJ 32
#define D_LSTM 64
#define G4 256        // 4 * D_LSTM
#define NH 4
#define DH 48
#define EMB 192

typedef float v2f __attribute__((ext_vector_type(2)));
typedef float v4f __attribute__((ext_vector_type(4)));
typedef _Float16 h2t __attribute__((ext_vector_type(2)));

__device__ __forceinline__ float sigmoid_f(float x) {
    return 1.f / (1.f + __expf(-x));
}
__device__ __forceinline__ float tanh_f(float x) {
    // robust: 1 - 2/(e^{2x}+1); handles +-inf of __expf
    float e = __expf(2.f * x);
    return 1.f - 2.f / (e + 1.f);
}

// ---------------------------------------------------------------------------
// Kernel 1: trajectory embed (ELU) + input-side LSTM gate precompute.
// Writes gates_x in layout [b][t][j][g] (g in {i,f,g,o} fastest) so that
// k_lstm lane j reads its 4 gates with ONE global_load_dwordx4.
// grid: 640 blocks (t), 256 threads
// ---------------------------------------------------------------------------
__global__ void __launch_bounds__(256) k_embed(
    const float* __restrict__ hist, const float* __restrict__ W1,
    const float* __restrict__ b1, const float* __restrict__ W_ih,
    const float* __restrict__ b_ih, const float* __restrict__ b_hh,
    float* __restrict__ gates_x)
{
    __shared__ float sh_hist[BATCH * D_IN];     // 320
    __shared__ float sh_traj[BATCH * D_TRAJ];   // 1280
    const int t = blockIdx.x, tid = threadIdx.x;

    for (int i = tid; i < BATCH * D_IN; i += 256)
        sh_hist[i] = hist[t * BATCH * D_IN + i];
    __syncthreads();

    for (int idx = tid; idx < BATCH * D_TRAJ; idx += 256) {
        int b = idx >> 5, h = idx & 31;
        float acc = b1[h];
        #pragma unroll
        for (int f = 0; f < D_IN; ++f)
            acc += sh_hist[b * D_IN + f] * W1[h * D_IN + f];
        sh_traj[idx] = acc > 0.f ? acc : (__expf(acc) - 1.f);   // ELU
    }
    __syncthreads();

    // one gate row per thread (torch order rows [i;f;g;o]), loop over batch
    float w[D_TRAJ];
    #pragma unroll
    for (int h = 0; h < D_TRAJ; ++h) w[h] = W_ih[tid * D_TRAJ + h];
    const float bias = b_ih[tid] + b_hh[tid];
    const int j = tid & 63, g = tid >> 6;       // unit, gate-type

    for (int b = 0; b < BATCH; ++b) {
        float acc = bias;
        #pragma unroll
        for (int h = 0; h < D_TRAJ; ++h)
            acc += sh_traj[b * D_TRAJ + h] * w[h];
        gates_x[((size_t)b * SEQ + t) * G4 + j * 4 + g] = acc;
    }
}

// ---------------------------------------------------------------------------
// Kernel 2: LSTM recurrence — ONE WAVE per chain, zero barriers, ZERO LDS.
// R2 post-mortem: f32 weights = 256 VGPR -> spill. R3 post-mortem: LDS
// h-exchange without barrier is UB (compiler may cache cross-lane data).
// Fix: f16-packed weights (128 VGPR) + v_dot2_f32_f16, h exchanged purely
// via __shfl (register broadcast, proven correct in R2).
// Lane j owns unit j. All 4 gate rows live as 32 half2 each.
// grid: 40 blocks x 64 threads.
// ---------------------------------------------------------------------------
__global__ void __launch_bounds__(64, 1) k_lstm(
    const float* __restrict__ gates_x, const float* __restrict__ W_hh,
    float* __restrict__ seq_out)
{
    const int b = blockIdx.x, j = threadIdx.x;

    // pack weight rows to half2: w?2[m] = (W?[j][2m], W?[j][2m+1])
    h2t wi2[32], wf2[32], wg2[32], wo2[32];
    const float* Wi = W_hh + (0 * 64 + j) * D_LSTM;
    const float* Wf = W_hh + (1 * 64 + j) * D_LSTM;
    const float* Wg = W_hh + (2 * 64 + j) * D_LSTM;
    const float* Wo = W_hh + (3 * 64 + j) * D_LSTM;
    #pragma unroll
    for (int m = 0; m < 32; ++m) {
        wi2[m] = (h2t){(_Float16)Wi[2 * m], (_Float16)Wi[2 * m + 1]};
        wf2[m] = (h2t){(_Float16)Wf[2 * m], (_Float16)Wf[2 * m + 1]};
        wg2[m] = (h2t){(_Float16)Wg[2 * m], (_Float16)Wg[2 * m + 1]};
        wo2[m] = (h2t){(_Float16)Wo[2 * m], (_Float16)Wo[2 * m + 1]};
    }

    const v4f* gxp = (const v4f*)(gates_x + (size_t)b * SEQ * G4);
    v4f gx_cur = gxp[j];
    v4f gx_nxt = gxp[64 + j];

    float h = 0.f, c = 0.f;
    float hpf = 0.f;   // packed (h[2m],h[2m+1]) as f16x2; lane 2m & 2m+1 hold pair m

    for (int t = 0; t < SEQ; ++t) {
        float ai = gx_cur.x, af = gx_cur.y, ag = gx_cur.z, ao = gx_cur.w;
        gx_cur = gx_nxt;
        int tp = (t + 2 < SEQ) ? t + 2 : SEQ - 1;
        gx_nxt = gxp[(size_t)tp * 64 + j];          // distance-2 prefetch

        #pragma unroll
        for (int m = 0; m < 32; ++m) {
            float pmf = __shfl(hpf, 2 * m, 64);     // register broadcast (readlane)
            h2t pm = __builtin_bit_cast(h2t, pmf);
            ai = __builtin_amdgcn_fdot2(wi2[m], pm, ai, false);
            af = __builtin_amdgcn_fdot2(wf2[m], pm, af, false);
            ag = __builtin_amdgcn_fdot2(wg2[m], pm, ag, false);
            ao = __builtin_amdgcn_fdot2(wo2[m], pm, ao, false);
        }

        c = sigmoid_f(af) * c + sigmoid_f(ai) * tanh_f(ag);
        h = sigmoid_f(ao) * tanh_f(c);
        seq_out[(size_t)(t * BATCH + b) * D_LSTM + j] = h;  // fire-and-forget

        // rebuild packed pair in-register: lanes 2m,2m+1 both hold pair m
        float hn = __shfl_xor(h, 1, 64);
        float lo = (j & 1) ? hn : h;
        float hi = (j & 1) ? h : hn;
        h2t hpk = {(_Float16)lo, (_Float16)hi};
        hpf = __builtin_bit_cast(float, hpk);
    }
}

// ---------------------------------------------------------------------------
// Kernel 3: multi-head attention over the 40-agent axis, per (head, t).
// grid: dim3(4, 640), 256 threads. Writes per-head o slice to ws.
// ---------------------------------------------------------------------------
#define SQK 49   // padded row stride for q/k/v in LDS (break 48-stride conflicts)
__global__ void __launch_bounds__(256) k_attn(
    const float* __restrict__ seq,
    const float* __restrict__ Wq, const float* __restrict__ bq,
    const float* __restrict__ Wk, const float* __restrict__ bk,
    const float* __restrict__ Wv, const float* __restrict__ bv,
    float* __restrict__ o_buf)
{
    const int h = blockIdx.x, t = blockIdx.y, tid = threadIdx.x;
    __shared__ float sseq[BATCH * D_LSTM];   // 2560
    __shared__ float sq[BATCH * SQK];        // 1960
    __shared__ float sk[BATCH * SQK];
    __shared__ float sv[BATCH * SQK];
    __shared__ float ss[BATCH * 41];         // scores, padded

    for (int i = tid; i < BATCH * D_LSTM; i += 256)
        sseq[i] = seq[t * BATCH * D_LSTM + i];
    __syncthreads();

    // q/k/v head slices: 3 * 1920 outputs, each a 64-dot
    for (int m = 0; m < 3; ++m) {
        const float* W    = (m == 0) ? Wq : (m == 1) ? Wk : Wv;
        const float* bias = (m == 0) ? bq : (m == 1) ? bk : bv;
        float* dst        = (m == 0) ? sq : (m == 1) ? sk : sv;
        for (int r = tid; r < BATCH * DH; r += 256) {
            int bi = r / DH, d = r % DH;
            int e = h * DH + d;
            const float* wrow = W + e * D_LSTM;
            const float* srow = sseq + bi * D_LSTM;
            float acc = bias[e];
            #pragma unroll 16
            for (int k = 0; k < D_LSTM; ++k) acc += srow[k] * wrow[k];
            dst[bi * SQK + d] = acc;
        }
    }
    __syncthreads();

    // scores = q k^T / 8
    for (int idx = tid; idx < BATCH * BATCH; idx += 256) {
        int i = idx / BATCH, j = idx % BATCH;
        float acc = 0.f;
        #pragma unroll 12
        for (int d = 0; d < DH; ++d) acc += sq[i * SQK + d] * sk[j * SQK + d];
        ss[i * 41 + j] = acc * 0.125f;
    }
    __syncthreads();

    // row softmax (one thread per row)
    if (tid < BATCH) {
        float m = -1e30f;
        for (int j = 0; j < BATCH; ++j) m = fmaxf(m, ss[tid * 41 + j]);
        float s = 0.f;
        for (int j = 0; j < BATCH; ++j) {
            float e = __expf(ss[tid * 41 + j] - m);
            ss[tid * 41 + j] = e;
            s += e;
        }
        float inv = 1.f / s;
        for (int j = 0; j < BATCH; ++j) ss[tid * 41 + j] *= inv;
    }
    __syncthreads();

    // o_h = a @ v ; write head slice into o_buf[t][b][h*48+d]
    for (int r = tid; r < BATCH * DH; r += 256) {
        int bi = r / DH, d = r % DH;
        float acc = 0.f;
        #pragma unroll 10
        for (int j = 0; j < BATCH; ++j) acc += ss[bi * 41 + j] * sv[j * SQK + d];
        o_buf[(t * BATCH + bi) * EMB + h * DH + d] = acc;
    }
}

// ---------------------------------------------------------------------------
// Kernel 4: GLU + residual + LayerNorm, per t. 256 threads.
// GLU phase: j = tid>>2 (output channel), bq = tid&3 (batch group of 10).
// LN phase: wave w handles rows {w, w+4, ...}; 64-lane shuffle reduction.
// ---------------------------------------------------------------------------
__global__ void __launch_bounds__(256) k_glu_ln(
    const float* __restrict__ seq, const float* __restrict__ obuf,
    const float* __restrict__ Wa, const float* __restrict__ ba,
    const float* __restrict__ Wg, const float* __restrict__ bg,
    const float* __restrict__ gamma, const float* __restrict__ beta,
    float* __restrict__ out)
{
    const int t = blockIdx.x, tid = threadIdx.x;
    __shared__ float so[BATCH * 193];       // o_t padded (192 -> 193)
    __shared__ float sy[BATCH * 65];        // y padded
    __shared__ float sseq[BATCH * D_LSTM];

    const float* ot = obuf + t * BATCH * EMB;
    for (int i = tid; i < BATCH * EMB; i += 256)
        so[(i / EMB) * 193 + (i % EMB)] = ot[i];
    for (int i = tid; i < BATCH * D_LSTM; i += 256)
        sseq[i] = seq[t * BATCH * D_LSTM + i];
    __syncthreads();

    const int j = tid >> 2, bgr = tid & 3;
    float acc_a[10], acc_g[10];
    #pragma unroll
    for (int bb = 0; bb < 10; ++bb) { acc_a[bb] = ba[j]; acc_g[bb] = bg[j]; }

    const float* wa = Wa + j * EMB;
    const float* wg = Wg + j * EMB;
    for (int p = 0; p < EMB; ++p) {
        float a = wa[p], g = wg[p];
        #pragma unroll
        for (int bb = 0; bb < 10; ++bb) {
            float o = so[(bgr + 4 * bb) * 193 + p];
            acc_a[bb] += o * a;
            acc_g[bb] += o * g;
        }
    }
    #pragma unroll
    for (int bb = 0; bb < 10; ++bb) {
        int b = bgr + 4 * bb;
        float tv = acc_a[bb] * sigmoid_f(acc_g[bb]);
        sy[b * 65 + j] = sseq[b * D_LSTM + j] + tv;
    }
    __syncthreads();

    const int w = tid >> 6, lane = tid & 63;
    const float gm = gamma[lane], bt = beta[lane];
    for (int rr = 0; rr < 10; ++rr) {
        int b = w + 4 * rr;
        float y = sy[b * 65 + lane];
        float s1 = y, s2 = y * y;
        #pragma unroll
        for (int m = 1; m < 64; m <<= 1) {
            s1 += __shfl_xor(s1, m, 64);
            s2 += __shfl_xor(s2, m, 64);
        }
        float mu  = s1 * (1.f / 64.f);
        float var = s2 * (1.f / 64.f) - mu * mu;
        float inv = rsqrtf(var + 1e-5f);
        out[t * BATCH * D_LSTM + b * D_LSTM + lane] = (y - mu) * inv * gm + bt;
    }
}

// ---------------------------------------------------------------------------
extern "C" void kernel_launch(void* const* d_in, const int* in_sizes, int n_in,
                              void* d_out, int out_size, void* d_ws, size_t ws_size,
                              hipStream_t stream)
{
    const float* hist = (const float*)d_in[0];
    // d_in[1] adj: unused (use_spatial=False)
    const float* W1   = (const float*)d_in[2];
    const float* b1   = (const float*)d_in[3];
    const float* W_ih = (const float*)d_in[4];
    const float* W_hh = (const float*)d_in[5];
    const float* b_ih = (const float*)d_in[6];
    const float* b_hh = (const float*)d_in[7];
    const float* Wq   = (const float*)d_in[8];
    const float* bq   = (const float*)d_in[9];
    const float* Wk   = (const float*)d_in[10];
    const float* bk   = (const float*)d_in[11];
    const float* Wv   = (const float*)d_in[12];
    const float* bv   = (const float*)d_in[13];
    const float* Wa   = (const float*)d_in[14];
    const float* ba   = (const float*)d_in[15];
    const float* Wg   = (const float*)d_in[16];
    const float* bg   = (const float*)d_in[17];
    const float* gamma = (const float*)d_in[18];
    const float* beta  = (const float*)d_in[19];
    float* out = (float*)d_out;

    float* ws = (float*)d_ws;
    float* gates_x = ws;                                   // 640*40*256 = 6,553,600 f
    float* seq     = ws + 6553600;                         // 640*40*64  = 1,638,400 f
    float* obuf    = ws + 6553600 + 1638400;               // 640*40*192 = 4,915,200 f

    hipLaunchKernelGGL(k_embed, dim3(SEQ), dim3(256), 0, stream,
                       hist, W1, b1, W_ih, b_ih, b_hh, gates_x);
    hipLaunchKernelGGL(k_lstm, dim3(BATCH), dim3(64), 0, stream,
                       gates_x, W_hh, seq);
    hipLaunchKernelGGL(k_attn, dim3(NH, SEQ), dim3(256), 0, stream,
                       seq, Wq, bq, Wk, bk, Wv, bv, obuf);
    hipLaunchKernelGGL(k_glu_ln, dim3(SEQ), dim3(256), 0, stream,
                       seq, obuf, Wa, ba, Wg, bg, gamma, beta, out);
}

// Round 5
// 993.181 us; speedup vs baseline: 2.0563x; 1.1232x over previous
//
#include <hip/hip_runtime.h>

#define SEQ 640
#define BATCH 40
#define D_IN 8
#define D_TRAJ 32
#define D_LSTM 64
#define G4 256        // 4 * D_LSTM
#define NH 4
#define DH 48
#define EMB 192

typedef float v2f __attribute__((ext_vector_type(2)));
typedef float v4f __attribute__((ext_vector_type(4)));
typedef _Float16 h2t __attribute__((ext_vector_type(2)));

__device__ __forceinline__ float sigmoid_f(float x) {
    return 1.f / (1.f + __expf(-x));
}
__device__ __forceinline__ float tanh_f(float x) {
    // robust: 1 - 2/(e^{2x}+1); handles +-inf of __expf
    float e = __expf(2.f * x);
    return 1.f - 2.f / (e + 1.f);
}

// ---------------------------------------------------------------------------
// Kernel 1: trajectory embed (ELU) + input-side LSTM gate precompute.
// Writes gates_x in layout [b][t][j][g] (g in {i,f,g,o} fastest) so that
// k_lstm lane j reads its 4 gates with ONE global_load_dwordx4.
// grid: 640 blocks (t), 256 threads
// ---------------------------------------------------------------------------
__global__ void __launch_bounds__(256) k_embed(
    const float* __restrict__ hist, const float* __restrict__ W1,
    const float* __restrict__ b1, const float* __restrict__ W_ih,
    const float* __restrict__ b_ih, const float* __restrict__ b_hh,
    float* __restrict__ gates_x)
{
    __shared__ float sh_hist[BATCH * D_IN];     // 320
    __shared__ float sh_traj[BATCH * D_TRAJ];   // 1280
    const int t = blockIdx.x, tid = threadIdx.x;

    for (int i = tid; i < BATCH * D_IN; i += 256)
        sh_hist[i] = hist[t * BATCH * D_IN + i];
    __syncthreads();

    for (int idx = tid; idx < BATCH * D_TRAJ; idx += 256) {
        int b = idx >> 5, h = idx & 31;
        float acc = b1[h];
        #pragma unroll
        for (int f = 0; f < D_IN; ++f)
            acc += sh_hist[b * D_IN + f] * W1[h * D_IN + f];
        sh_traj[idx] = acc > 0.f ? acc : (__expf(acc) - 1.f);   // ELU
    }
    __syncthreads();

    // one gate row per thread (torch order rows [i;f;g;o]), loop over batch
    float w[D_TRAJ];
    #pragma unroll
    for (int h = 0; h < D_TRAJ; ++h) w[h] = W_ih[tid * D_TRAJ + h];
    const float bias = b_ih[tid] + b_hh[tid];
    const int j = tid & 63, g = tid >> 6;       // unit, gate-type

    for (int b = 0; b < BATCH; ++b) {
        float acc = bias;
        #pragma unroll
        for (int h = 0; h < D_TRAJ; ++h)
            acc += sh_traj[b * D_TRAJ + h] * w[h];
        gates_x[((size_t)b * SEQ + t) * G4 + j * 4 + g] = acc;
    }
}

// ---------------------------------------------------------------------------
// Kernel 2: LSTM recurrence — ONE WAVE per chain, zero barriers, ZERO LDS.
// R2: f32 weights = 256 VGPR -> spill (fixed: f16x2 + v_dot2_f32_f16).
// R3: barrier-free LDS exchange = UB (fixed: register exchange).
// R4 post-mortem: __shfl(hpf, const) compiled to ds_bpermute; compiler
// serialized 32 LDS-latency exposures -> ~2000 cyc/step. Fix: broadcast via
// __builtin_amdgcn_readlane (v_readlane -> SGPR, ~4 cyc, no LDS); fdot2
// takes the SGPR as its single scalar operand.
// grid: 40 blocks x 64 threads.
// ---------------------------------------------------------------------------
__global__ void __launch_bounds__(64, 1) k_lstm(
    const float* __restrict__ gates_x, const float* __restrict__ W_hh,
    float* __restrict__ seq_out)
{
    const int b = blockIdx.x, j = threadIdx.x;

    // pack weight rows to half2: w?2[m] = (W?[j][2m], W?[j][2m+1])
    h2t wi2[32], wf2[32], wg2[32], wo2[32];
    const float* Wi = W_hh + (0 * 64 + j) * D_LSTM;
    const float* Wf = W_hh + (1 * 64 + j) * D_LSTM;
    const float* Wg = W_hh + (2 * 64 + j) * D_LSTM;
    const float* Wo = W_hh + (3 * 64 + j) * D_LSTM;
    #pragma unroll
    for (int m = 0; m < 32; ++m) {
        wi2[m] = (h2t){(_Float16)Wi[2 * m], (_Float16)Wi[2 * m + 1]};
        wf2[m] = (h2t){(_Float16)Wf[2 * m], (_Float16)Wf[2 * m + 1]};
        wg2[m] = (h2t){(_Float16)Wg[2 * m], (_Float16)Wg[2 * m + 1]};
        wo2[m] = (h2t){(_Float16)Wo[2 * m], (_Float16)Wo[2 * m + 1]};
    }

    const v4f* gxp = (const v4f*)(gates_x + (size_t)b * SEQ * G4);
    v4f gx_cur = gxp[j];
    v4f gx_nxt = gxp[64 + j];

    float h = 0.f, c = 0.f;
    float hpf = 0.f;   // packed (h[2m],h[2m+1]) as f16x2; lanes 2m,2m+1 hold pair m

    for (int t = 0; t < SEQ; ++t) {
        float ai = gx_cur.x, af = gx_cur.y, ag = gx_cur.z, ao = gx_cur.w;
        gx_cur = gx_nxt;
        int tp = (t + 2 < SEQ) ? t + 2 : SEQ - 1;
        gx_nxt = gxp[(size_t)tp * 64 + j];          // distance-2 prefetch

        const int hbits = __builtin_bit_cast(int, hpf);
        #pragma unroll
        for (int m = 0; m < 32; ++m) {
            // v_readlane_b32 -> SGPR: no LDS, ~4 cyc, 32 independent broadcasts
            int pmi = __builtin_amdgcn_readlane(hbits, 2 * m);
            h2t pm = __builtin_bit_cast(h2t, pmi);
            ai = __builtin_amdgcn_fdot2(wi2[m], pm, ai, false);
            af = __builtin_amdgcn_fdot2(wf2[m], pm, af, false);
            ag = __builtin_amdgcn_fdot2(wg2[m], pm, ag, false);
            ao = __builtin_amdgcn_fdot2(wo2[m], pm, ao, false);
        }

        c = sigmoid_f(af) * c + sigmoid_f(ai) * tanh_f(ag);
        h = sigmoid_f(ao) * tanh_f(c);
        seq_out[(size_t)(t * BATCH + b) * D_LSTM + j] = h;  // fire-and-forget

        // rebuild packed pair in-register: lanes 2m,2m+1 both hold pair m
        float hn = __shfl_xor(h, 1, 64);
        float lo = (j & 1) ? hn : h;
        float hi = (j & 1) ? h : hn;
        h2t hpk = {(_Float16)lo, (_Float16)hi};
        hpf = __builtin_bit_cast(float, hpk);
    }
}

// ---------------------------------------------------------------------------
// Kernel 3: multi-head attention over the 40-agent axis, per (head, t).
// grid: dim3(4, 640), 256 threads. Writes per-head o slice to ws.
// ---------------------------------------------------------------------------
#define SQK 49   // padded row stride for q/k/v in LDS (break 48-stride conflicts)
__global__ void __launch_bounds__(256) k_attn(
    const float* __restrict__ seq,
    const float* __restrict__ Wq, const float* __restrict__ bq,
    const float* __restrict__ Wk, const float* __restrict__ bk,
    const float* __restrict__ Wv, const float* __restrict__ bv,
    float* __restrict__ o_buf)
{
    const int h = blockIdx.x, t = blockIdx.y, tid = threadIdx.x;
    __shared__ float sseq[BATCH * D_LSTM];   // 2560
    __shared__ float sq[BATCH * SQK];        // 1960
    __shared__ float sk[BATCH * SQK];
    __shared__ float sv[BATCH * SQK];
    __shared__ float ss[BATCH * 41];         // scores, padded

    for (int i = tid; i < BATCH * D_LSTM; i += 256)
        sseq[i] = seq[t * BATCH * D_LSTM + i];
    __syncthreads();

    // q/k/v head slices: 3 * 1920 outputs, each a 64-dot
    for (int m = 0; m < 3; ++m) {
        const float* W    = (m == 0) ? Wq : (m == 1) ? Wk : Wv;
        const float* bias = (m == 0) ? bq : (m == 1) ? bk : bv;
        float* dst        = (m == 0) ? sq : (m == 1) ? sk : sv;
        for (int r = tid; r < BATCH * DH; r += 256) {
            int bi = r / DH, d = r % DH;
            int e = h * DH + d;
            const float* wrow = W + e * D_LSTM;
            const float* srow = sseq + bi * D_LSTM;
            float acc = bias[e];
            #pragma unroll 16
            for (int k = 0; k < D_LSTM; ++k) acc += srow[k] * wrow[k];
            dst[bi * SQK + d] = acc;
        }
    }
    __syncthreads();

    // scores = q k^T / 8
    for (int idx = tid; idx < BATCH * BATCH; idx += 256) {
        int i = idx / BATCH, j = idx % BATCH;
        float acc = 0.f;
        #pragma unroll 12
        for (int d = 0; d < DH; ++d) acc += sq[i * SQK + d] * sk[j * SQK + d];
        ss[i * 41 + j] = acc * 0.125f;
    }
    __syncthreads();

    // row softmax (one thread per row)
    if (tid < BATCH) {
        float m = -1e30f;
        for (int j = 0; j < BATCH; ++j) m = fmaxf(m, ss[tid * 41 + j]);
        float s = 0.f;
        for (int j = 0; j < BATCH; ++j) {
            float e = __expf(ss[tid * 41 + j] - m);
            ss[tid * 41 + j] = e;
            s += e;
        }
        float inv = 1.f / s;
        for (int j = 0; j < BATCH; ++j) ss[tid * 41 + j] *= inv;
    }
    __syncthreads();

    // o_h = a @ v ; write head slice into o_buf[t][b][h*48+d]
    for (int r = tid; r < BATCH * DH; r += 256) {
        int bi = r / DH, d = r % DH;
        float acc = 0.f;
        #pragma unroll 10
        for (int j = 0; j < BATCH; ++j) acc += ss[bi * 41 + j] * sv[j * SQK + d];
        o_buf[(t * BATCH + bi) * EMB + h * DH + d] = acc;
    }
}

// ---------------------------------------------------------------------------
// Kernel 4: GLU + residual + LayerNorm, per t. 256 threads.
// GLU phase: j = tid>>2 (output channel), bq = tid&3 (batch group of 10).
// LN phase: wave w handles rows {w, w+4, ...}; 64-lane shuffle reduction.
// ---------------------------------------------------------------------------
__global__ void __launch_bounds__(256) k_glu_ln(
    const float* __restrict__ seq, const float* __restrict__ obuf,
    const float* __restrict__ Wa, const float* __restrict__ ba,
    const float* __restrict__ Wg, const float* __restrict__ bg,
    const float* __restrict__ gamma, const float* __restrict__ beta,
    float* __restrict__ out)
{
    const int t = blockIdx.x, tid = threadIdx.x;
    __shared__ float so[BATCH * 193];       // o_t padded (192 -> 193)
    __shared__ float sy[BATCH * 65];        // y padded
    __shared__ float sseq[BATCH * D_LSTM];

    const float* ot = obuf + t * BATCH * EMB;
    for (int i = tid; i < BATCH * EMB; i += 256)
        so[(i / EMB) * 193 + (i % EMB)] = ot[i];
    for (int i = tid; i < BATCH * D_LSTM; i += 256)
        sseq[i] = seq[t * BATCH * D_LSTM + i];
    __syncthreads();

    const int j = tid >> 2, bgr = tid & 3;
    float acc_a[10], acc_g[10];
    #pragma unroll
    for (int bb = 0; bb < 10; ++bb) { acc_a[bb] = ba[j]; acc_g[bb] = bg[j]; }

    const float* wa = Wa + j * EMB;
    const float* wg = Wg + j * EMB;
    for (int p = 0; p < EMB; ++p) {
        float a = wa[p], g = wg[p];
        #pragma unroll
        for (int bb = 0; bb < 10; ++bb) {
            float o = so[(bgr + 4 * bb) * 193 + p];
            acc_a[bb] += o * a;
            acc_g[bb] += o * g;
        }
    }
    #pragma unroll
    for (int bb = 0; bb < 10; ++bb) {
        int b = bgr + 4 * bb;
        float tv = acc_a[bb] * sigmoid_f(acc_g[bb]);
        sy[b * 65 + j] = sseq[b * D_LSTM + j] + tv;
    }
    __syncthreads();

    const int w = tid >> 6, lane = tid & 63;
    const float gm = gamma[lane], bt = beta[lane];
    for (int rr = 0; rr < 10; ++rr) {
        int b = w + 4 * rr;
        float y = sy[b * 65 + lane];
        float s1 = y, s2 = y * y;
        #pragma unroll
        for (int m = 1; m < 64; m <<= 1) {
            s1 += __shfl_xor(s1, m, 64);
            s2 += __shfl_xor(s2, m, 64);
        }
        float mu  = s1 * (1.f / 64.f);
        float var = s2 * (1.f / 64.f) - mu * mu;
        float inv = rsqrtf(var + 1e-5f);
        out[t * BATCH * D_LSTM + b * D_LSTM + lane] = (y - mu) * inv * gm + bt;
    }
}

// ---------------------------------------------------------------------------
extern "C" void kernel_launch(void* const* d_in, const int* in_sizes, int n_in,
                              void* d_out, int out_size, void* d_ws, size_t ws_size,
                              hipStream_t stream)
{
    const float* hist = (const float*)d_in[0];
    // d_in[1] adj: unused (use_spatial=False)
    const float* W1   = (const float*)d_in[2];
    const float* b1   = (const float*)d_in[3];
    const float* W_ih = (const float*)d_in[4];
    const float* W_hh = (const float*)d_in[5];
    const float* b_ih = (const float*)d_in[6];
    const float* b_hh = (const float*)d_in[7];
    const float* Wq   = (const float*)d_in[8];
    const float* bq   = (const float*)d_in[9];
    const float* Wk   = (const float*)d_in[10];
    const float* bk   = (const float*)d_in[11];
    const float* Wv   = (const float*)d_in[12];
    const float* bv   = (const float*)d_in[13];
    const float* Wa   = (const float*)d_in[14];
    const float* ba   = (const float*)d_in[15];
    const float* Wg   = (const float*)d_in[16];
    const float* bg   = (const float*)d_in[17];
    const float* gamma = (const float*)d_in[18];
    const float* beta  = (const float*)d_in[19];
    float* out = (float*)d_out;

    float* ws = (float*)d_ws;
    float* gates_x = ws;                                   // 640*40*256 = 6,553,600 f
    float* seq     = ws + 6553600;                         // 640*40*64  = 1,638,400 f
    float* obuf    = ws + 6553600 + 1638400;               // 640*40*192 = 4,915,200 f

    hipLaunchKernelGGL(k_embed, dim3(SEQ), dim3(256), 0, stream,
                       hist, W1, b1, W_ih, b_ih, b_hh, gates_x);
    hipLaunchKernelGGL(k_lstm, dim3(BATCH), dim3(64), 0, stream,
                       gates_x, W_hh, seq);
    hipLaunchKernelGGL(k_attn, dim3(NH, SEQ), dim3(256), 0, stream,
                       seq, Wq, bq, Wk, bk, Wv, bv, obuf);
    hipLaunchKernelGGL(k_glu_ln, dim3(SEQ), dim3(256), 0, stream,
                       seq, obuf, Wa, ba, Wg, bg, gamma, beta, out);
}

// Round 6
// 691.899 us; speedup vs baseline: 2.9517x; 1.4354x over previous
//
#include <hip/hip_runtime.h>

#define SEQ 640
#define BATCH 40
#define D_IN 8
#define D_TRAJ 32
#define D_LSTM 64
#define G4 256        // 4 * D_LSTM
#define NH 4
#define DH 48
#define EMB 192

typedef float v2f __attribute__((ext_vector_type(2)));
typedef float v4f __attribute__((ext_vector_type(4)));
typedef _Float16 h2t __attribute__((ext_vector_type(2)));

__device__ __forceinline__ float sigmoid_f(float x) {
    return 1.f / (1.f + __expf(-x));
}
__device__ __forceinline__ float tanh_f(float x) {
    // robust: 1 - 2/(e^{2x}+1); handles +-inf of __expf
    float e = __expf(2.f * x);
    return 1.f - 2.f / (e + 1.f);
}

// ---------------------------------------------------------------------------
// Kernel 1: trajectory embed (ELU) + input-side LSTM gate precompute.
// Writes gates_x in layout [b][t][j][g] (g in {i,f,g,o} fastest) so that
// k_lstm lane j reads its 4 gates with ONE global_load_dwordx4.
// grid: 640 blocks (t), 256 threads
// ---------------------------------------------------------------------------
__global__ void __launch_bounds__(256) k_embed(
    const float* __restrict__ hist, const float* __restrict__ W1,
    const float* __restrict__ b1, const float* __restrict__ W_ih,
    const float* __restrict__ b_ih, const float* __restrict__ b_hh,
    float* __restrict__ gates_x)
{
    __shared__ float sh_hist[BATCH * D_IN];     // 320
    __shared__ float sh_traj[BATCH * D_TRAJ];   // 1280
    const int t = blockIdx.x, tid = threadIdx.x;

    for (int i = tid; i < BATCH * D_IN; i += 256)
        sh_hist[i] = hist[t * BATCH * D_IN + i];
    __syncthreads();

    for (int idx = tid; idx < BATCH * D_TRAJ; idx += 256) {
        int b = idx >> 5, h = idx & 31;
        float acc = b1[h];
        #pragma unroll
        for (int f = 0; f < D_IN; ++f)
            acc += sh_hist[b * D_IN + f] * W1[h * D_IN + f];
        sh_traj[idx] = acc > 0.f ? acc : (__expf(acc) - 1.f);   // ELU
    }
    __syncthreads();

    // one gate row per thread (torch order rows [i;f;g;o]), loop over batch
    float w[D_TRAJ];
    #pragma unroll
    for (int h = 0; h < D_TRAJ; ++h) w[h] = W_ih[tid * D_TRAJ + h];
    const float bias = b_ih[tid] + b_hh[tid];
    const int j = tid & 63, g = tid >> 6;       // unit, gate-type

    for (int b = 0; b < BATCH; ++b) {
        float acc = bias;
        #pragma unroll
        for (int h = 0; h < D_TRAJ; ++h)
            acc += sh_traj[b * D_TRAJ + h] * w[h];
        gates_x[((size_t)b * SEQ + t) * G4 + j * 4 + g] = acc;
    }
}

// ---------------------------------------------------------------------------
// Kernel 2: LSTM recurrence — ONE WAVE per chain, zero barriers, ZERO LDS.
// R2: f32 weights = 256 VGPR -> spill (fixed: f16x2 + v_dot2_f32_f16).
// R3: barrier-free LDS exchange = UB (fixed: register exchange).
// R4: __shfl broadcast = ds_bpermute, 32 serialized LDS latencies
//     (fixed: __builtin_amdgcn_readlane -> SGPR, ~4 cyc, no LDS).
// grid: 40 blocks x 64 threads.
// ---------------------------------------------------------------------------
__global__ void __launch_bounds__(64, 1) k_lstm(
    const float* __restrict__ gates_x, const float* __restrict__ W_hh,
    float* __restrict__ seq_out)
{
    const int b = blockIdx.x, j = threadIdx.x;

    // pack weight rows to half2: w?2[m] = (W?[j][2m], W?[j][2m+1])
    h2t wi2[32], wf2[32], wg2[32], wo2[32];
    const float* Wi = W_hh + (0 * 64 + j) * D_LSTM;
    const float* Wf = W_hh + (1 * 64 + j) * D_LSTM;
    const float* Wg = W_hh + (2 * 64 + j) * D_LSTM;
    const float* Wo = W_hh + (3 * 64 + j) * D_LSTM;
    #pragma unroll
    for (int m = 0; m < 32; ++m) {
        wi2[m] = (h2t){(_Float16)Wi[2 * m], (_Float16)Wi[2 * m + 1]};
        wf2[m] = (h2t){(_Float16)Wf[2 * m], (_Float16)Wf[2 * m + 1]};
        wg2[m] = (h2t){(_Float16)Wg[2 * m], (_Float16)Wg[2 * m + 1]};
        wo2[m] = (h2t){(_Float16)Wo[2 * m], (_Float16)Wo[2 * m + 1]};
    }

    const v4f* gxp = (const v4f*)(gates_x + (size_t)b * SEQ * G4);
    v4f gx_cur = gxp[j];
    v4f gx_nxt = gxp[64 + j];

    float h = 0.f, c = 0.f;
    float hpf = 0.f;   // packed (h[2m],h[2m+1]) as f16x2; lanes 2m,2m+1 hold pair m

    for (int t = 0; t < SEQ; ++t) {
        float ai = gx_cur.x, af = gx_cur.y, ag = gx_cur.z, ao = gx_cur.w;
        gx_cur = gx_nxt;
        int tp = (t + 2 < SEQ) ? t + 2 : SEQ - 1;
        gx_nxt = gxp[(size_t)tp * 64 + j];          // distance-2 prefetch

        const int hbits = __builtin_bit_cast(int, hpf);
        #pragma unroll
        for (int m = 0; m < 32; ++m) {
            // v_readlane_b32 -> SGPR: no LDS, ~4 cyc, 32 independent broadcasts
            int pmi = __builtin_amdgcn_readlane(hbits, 2 * m);
            h2t pm = __builtin_bit_cast(h2t, pmi);
            ai = __builtin_amdgcn_fdot2(wi2[m], pm, ai, false);
            af = __builtin_amdgcn_fdot2(wf2[m], pm, af, false);
            ag = __builtin_amdgcn_fdot2(wg2[m], pm, ag, false);
            ao = __builtin_amdgcn_fdot2(wo2[m], pm, ao, false);
        }

        c = sigmoid_f(af) * c + sigmoid_f(ai) * tanh_f(ag);
        h = sigmoid_f(ao) * tanh_f(c);
        seq_out[(size_t)(t * BATCH + b) * D_LSTM + j] = h;  // fire-and-forget

        // rebuild packed pair in-register: lanes 2m,2m+1 both hold pair m
        float hn = __shfl_xor(h, 1, 64);
        float lo = (j & 1) ? hn : h;
        float hi = (j & 1) ? h : hn;
        h2t hpk = {(_Float16)lo, (_Float16)hi};
        hpf = __builtin_bit_cast(float, hpk);
    }
}

// ---------------------------------------------------------------------------
// Kernel 3: multi-head attention, per (head, t). R5 post-mortem: projection
// paid 1 scalar-LDS read + 1 UNCOALESCED global weight read per FMA in the
// inner loop (64 cache lines per load instr) -> latency-bound, VALUBusy 11%.
// Fix: stage the head's W slices in LDS once per block (coalesced, L2-hot),
// register-block the projection: per k, 3 conflict-free sW reads (+1-pad
// stride 65) + 10 wave-uniform sA broadcasts feed 30 FMAs.
// LDS 78.5 KB -> 2 blocks/CU. grid: dim3(4, 640), 256 threads.
// ---------------------------------------------------------------------------
#define SQK 49   // padded row stride for q/k/v in LDS (break 48-stride conflicts)
#define SWS 65   // padded row stride for staged weights / seq rows
__global__ void __launch_bounds__(256) k_attn(
    const float* __restrict__ seq,
    const float* __restrict__ Wq, const float* __restrict__ bq,
    const float* __restrict__ Wk, const float* __restrict__ bk,
    const float* __restrict__ Wv, const float* __restrict__ bv,
    float* __restrict__ o_buf)
{
    const int h = blockIdx.x, t = blockIdx.y, tid = threadIdx.x;
    __shared__ float sW[144 * SWS];      // rows m*48+d (m in {q,k,v}), cols k
    __shared__ float sb[144];            // head bias slices
    __shared__ float sA[BATCH * SWS];    // seq_t rows
    __shared__ float sq[BATCH * SQK];
    __shared__ float sk[BATCH * SQK];
    __shared__ float sv[BATCH * SQK];
    __shared__ float ss[BATCH * 41];     // scores, padded

    // ---- stage head weight slices (coalesced: one wave covers one row) ----
    for (int i = tid; i < 144 * 64; i += 256) {
        int row = i >> 6, k = i & 63;
        int m = row / 48, d = row - m * 48;
        const float* W = (m == 0) ? Wq : (m == 1) ? Wk : Wv;
        sW[row * SWS + k] = W[(h * DH + d) * D_LSTM + k];
    }
    if (tid < 144) {
        int m = tid / 48, d = tid - m * 48;
        const float* B = (m == 0) ? bq : (m == 1) ? bk : bv;
        sb[tid] = B[h * DH + d];
    }
    for (int i = tid; i < BATCH * D_LSTM; i += 256)
        sA[(i >> 6) * SWS + (i & 63)] = seq[t * BATCH * D_LSTM + i];
    __syncthreads();

    // ---- q/k/v projection, register-blocked ----
    // lane -> cols {lane, lane+64, lane+128 (lanes<16)}; row-group rg -> 10 rows
    const int lane = tid & 63, rg = tid >> 6;
    const int b0 = rg * 10;
    const int c2row = (lane < 16) ? (lane + 128) : 0;   // clamped; acc2 unused if invalid
    float acc0[10], acc1[10], acc2[10];
    {
        float bias0 = sb[lane], bias1 = sb[lane + 64];
        float bias2 = (lane < 16) ? sb[lane + 128] : 0.f;
        #pragma unroll
        for (int r = 0; r < 10; ++r) { acc0[r] = bias0; acc1[r] = bias1; acc2[r] = bias2; }
    }
    #pragma unroll 4
    for (int k = 0; k < D_LSTM; ++k) {
        float w0 = sW[lane * SWS + k];
        float w1 = sW[(lane + 64) * SWS + k];
        float w2 = sW[c2row * SWS + k];
        float a[10];
        #pragma unroll
        for (int r = 0; r < 10; ++r) a[r] = sA[(b0 + r) * SWS + k];  // broadcast
        #pragma unroll
        for (int r = 0; r < 10; ++r) {
            acc0[r] += a[r] * w0;
            acc1[r] += a[r] * w1;
            acc2[r] += a[r] * w2;
        }
    }
    // write projection results into sq/sk/sv (padded)
    {
        int m0 = lane / 48, d0 = lane - m0 * 48;
        float* dst0 = (m0 == 0) ? sq : (m0 == 1) ? sk : sv;
        int c1 = lane + 64, m1 = c1 / 48, d1 = c1 - m1 * 48;
        float* dst1 = (m1 == 0) ? sq : (m1 == 1) ? sk : sv;
        #pragma unroll
        for (int r = 0; r < 10; ++r) {
            dst0[(b0 + r) * SQK + d0] = acc0[r];
            dst1[(b0 + r) * SQK + d1] = acc1[r];
        }
        if (lane < 16) {
            int c2 = lane + 128, d2 = c2 - 96;   // m2 == 2 -> v
            #pragma unroll
            for (int r = 0; r < 10; ++r) sv[(b0 + r) * SQK + d2] = acc2[r];
        }
    }
    __syncthreads();

    // ---- scores = q k^T / 8 ----
    for (int idx = tid; idx < BATCH * BATCH; idx += 256) {
        int i = idx / BATCH, j = idx % BATCH;
        float acc = 0.f;
        #pragma unroll 12
        for (int d = 0; d < DH; ++d) acc += sq[i * SQK + d] * sk[j * SQK + d];
        ss[i * 41 + j] = acc * 0.125f;
    }
    __syncthreads();

    // ---- row softmax (one thread per row) ----
    if (tid < BATCH) {
        float m = -1e30f;
        for (int j = 0; j < BATCH; ++j) m = fmaxf(m, ss[tid * 41 + j]);
        float s = 0.f;
        for (int j = 0; j < BATCH; ++j) {
            float e = __expf(ss[tid * 41 + j] - m);
            ss[tid * 41 + j] = e;
            s += e;
        }
        float inv = 1.f / s;
        for (int j = 0; j < BATCH; ++j) ss[tid * 41 + j] *= inv;
    }
    __syncthreads();

    // ---- o_h = a @ v ; write head slice into o_buf[t][b][h*48+d] ----
    for (int r = tid; r < BATCH * DH; r += 256) {
        int bi = r / DH, d = r % DH;
        float acc = 0.f;
        #pragma unroll 10
        for (int j = 0; j < BATCH; ++j) acc += ss[bi * 41 + j] * sv[j * SQK + d];
        o_buf[(t * BATCH + bi) * EMB + h * DH + d] = acc;
    }
}

// ---------------------------------------------------------------------------
// Kernel 4: GLU + residual + LayerNorm, per t. 256 threads.
// GLU phase: j = tid>>2 (output channel), bq = tid&3 (batch group of 10).
// LN phase: wave w handles rows {w, w+4, ...}; 64-lane shuffle reduction.
// ---------------------------------------------------------------------------
__global__ void __launch_bounds__(256) k_glu_ln(
    const float* __restrict__ seq, const float* __restrict__ obuf,
    const float* __restrict__ Wa, const float* __restrict__ ba,
    const float* __restrict__ Wg, const float* __restrict__ bg,
    const float* __restrict__ gamma, const float* __restrict__ beta,
    float* __restrict__ out)
{
    const int t = blockIdx.x, tid = threadIdx.x;
    __shared__ float so[BATCH * 193];       // o_t padded (192 -> 193)
    __shared__ float sy[BATCH * 65];        // y padded
    __shared__ float sseq[BATCH * D_LSTM];

    const float* ot = obuf + t * BATCH * EMB;
    for (int i = tid; i < BATCH * EMB; i += 256)
        so[(i / EMB) * 193 + (i % EMB)] = ot[i];
    for (int i = tid; i < BATCH * D_LSTM; i += 256)
        sseq[i] = seq[t * BATCH * D_LSTM + i];
    __syncthreads();

    const int j = tid >> 2, bgr = tid & 3;
    float acc_a[10], acc_g[10];
    #pragma unroll
    for (int bb = 0; bb < 10; ++bb) { acc_a[bb] = ba[j]; acc_g[bb] = bg[j]; }

    const float* wa = Wa + j * EMB;
    const float* wg = Wg + j * EMB;
    for (int p = 0; p < EMB; ++p) {
        float a = wa[p], g = wg[p];
        #pragma unroll
        for (int bb = 0; bb < 10; ++bb) {
            float o = so[(bgr + 4 * bb) * 193 + p];
            acc_a[bb] += o * a;
            acc_g[bb] += o * g;
        }
    }
    #pragma unroll
    for (int bb = 0; bb < 10; ++bb) {
        int b = bgr + 4 * bb;
        float tv = acc_a[bb] * sigmoid_f(acc_g[bb]);
        sy[b * 65 + j] = sseq[b * D_LSTM + j] + tv;
    }
    __syncthreads();

    const int w = tid >> 6, lane = tid & 63;
    const float gm = gamma[lane], bt = beta[lane];
    for (int rr = 0; rr < 10; ++rr) {
        int b = w + 4 * rr;
        float y = sy[b * 65 + lane];
        float s1 = y, s2 = y * y;
        #pragma unroll
        for (int m = 1; m < 64; m <<= 1) {
            s1 += __shfl_xor(s1, m, 64);
            s2 += __shfl_xor(s2, m, 64);
        }
        float mu  = s1 * (1.f / 64.f);
        float var = s2 * (1.f / 64.f) - mu * mu;
        float inv = rsqrtf(var + 1e-5f);
        out[t * BATCH * D_LSTM + b * D_LSTM + lane] = (y - mu) * inv * gm + bt;
    }
}

// ---------------------------------------------------------------------------
extern "C" void kernel_launch(void* const* d_in, const int* in_sizes, int n_in,
                              void* d_out, int out_size, void* d_ws, size_t ws_size,
                              hipStream_t stream)
{
    const float* hist = (const float*)d_in[0];
    // d_in[1] adj: unused (use_spatial=False)
    const float* W1   = (const float*)d_in[2];
    const float* b1   = (const float*)d_in[3];
    const float* W_ih = (const float*)d_in[4];
    const float* W_hh = (const float*)d_in[5];
    const float* b_ih = (const float*)d_in[6];
    const float* b_hh = (const float*)d_in[7];
    const float* Wq   = (const float*)d_in[8];
    const float* bq   = (const float*)d_in[9];
    const float* Wk   = (const float*)d_in[10];
    const float* bk   = (const float*)d_in[11];
    const float* Wv   = (const float*)d_in[12];
    const float* bv   = (const float*)d_in[13];
    const float* Wa   = (const float*)d_in[14];
    const float* ba   = (const float*)d_in[15];
    const float* Wg   = (const float*)d_in[16];
    const float* bg   = (const float*)d_in[17];
    const float* gamma = (const float*)d_in[18];
    const float* beta  = (const float*)d_in[19];
    float* out = (float*)d_out;

    float* ws = (float*)d_ws;
    float* gates_x = ws;                                   // 640*40*256 = 6,553,600 f
    float* seq     = ws + 6553600;                         // 640*40*64  = 1,638,400 f
    float* obuf    = ws + 6553600 + 1638400;               // 640*40*192 = 4,915,200 f

    hipLaunchKernelGGL(k_embed, dim3(SEQ), dim3(256), 0, stream,
                       hist, W1, b1, W_ih, b_ih, b_hh, gates_x);
    hipLaunchKernelGGL(k_lstm, dim3(BATCH), dim3(64), 0, stream,
                       gates_x, W_hh, seq);
    hipLaunchKernelGGL(k_attn, dim3(NH, SEQ), dim3(256), 0, stream,
                       seq, Wq, bq, Wk, bk, Wv, bv, obuf);
    hipLaunchKernelGGL(k_glu_ln, dim3(SEQ), dim3(256), 0, stream,
                       seq, obuf, Wa, ba, Wg, bg, gamma, beta, out);
}

// Round 7
// 642.470 us; speedup vs baseline: 3.1788x; 1.0769x over previous
//
#include <hip/hip_runtime.h>

#define SEQ 640
#define BATCH 40
#define D_IN 8
#define D_TRAJ 32
#define D_LSTM 64
#define G4 256        // 4 * D_LSTM
#define NH 4
#define DH 48
#define EMB 192

typedef float v2f __attribute__((ext_vector_type(2)));
typedef float v4f __attribute__((ext_vector_type(4)));
typedef _Float16 h2t __attribute__((ext_vector_type(2)));

__device__ __forceinline__ float sigmoid_f(float x) {
    return 1.f / (1.f + __expf(-x));
}
__device__ __forceinline__ float tanh_f(float x) {
    // robust: 1 - 2/(e^{2x}+1); handles +-inf of __expf
    float e = __expf(2.f * x);
    return 1.f - 2.f / (e + 1.f);
}

// ---------------------------------------------------------------------------
// Kernel 1: trajectory embed (ELU) + input-side LSTM gate precompute.
// Writes gates_x in layout [b][t][j][g] (g in {i,f,g,o} fastest) so that
// k_lstm lane j reads its 4 gates with ONE global_load_dwordx4.
// grid: 640 blocks (t), 256 threads
// ---------------------------------------------------------------------------
__global__ void __launch_bounds__(256) k_embed(
    const float* __restrict__ hist, const float* __restrict__ W1,
    const float* __restrict__ b1, const float* __restrict__ W_ih,
    const float* __restrict__ b_ih, const float* __restrict__ b_hh,
    float* __restrict__ gates_x)
{
    __shared__ float sh_hist[BATCH * D_IN];     // 320
    __shared__ float sh_traj[BATCH * D_TRAJ];   // 1280
    const int t = blockIdx.x, tid = threadIdx.x;

    for (int i = tid; i < BATCH * D_IN; i += 256)
        sh_hist[i] = hist[t * BATCH * D_IN + i];
    __syncthreads();

    for (int idx = tid; idx < BATCH * D_TRAJ; idx += 256) {
        int b = idx >> 5, h = idx & 31;
        float acc = b1[h];
        #pragma unroll
        for (int f = 0; f < D_IN; ++f)
            acc += sh_hist[b * D_IN + f] * W1[h * D_IN + f];
        sh_traj[idx] = acc > 0.f ? acc : (__expf(acc) - 1.f);   // ELU
    }
    __syncthreads();

    // one gate row per thread (torch order rows [i;f;g;o]), loop over batch
    float w[D_TRAJ];
    #pragma unroll
    for (int h = 0; h < D_TRAJ; ++h) w[h] = W_ih[tid * D_TRAJ + h];
    const float bias = b_ih[tid] + b_hh[tid];
    const int j = tid & 63, g = tid >> 6;       // unit, gate-type

    for (int b = 0; b < BATCH; ++b) {
        float acc = bias;
        #pragma unroll
        for (int h = 0; h < D_TRAJ; ++h)
            acc += sh_traj[b * D_TRAJ + h] * w[h];
        gates_x[((size_t)b * SEQ + t) * G4 + j * 4 + g] = acc;
    }
}

// ---------------------------------------------------------------------------
// Kernel 2: LSTM recurrence — ONE WAVE per chain, zero barriers, ZERO LDS.
// R2: f32 weights = 256 VGPR -> spill (fixed: f16x2 + v_dot2_f32_f16).
// R3: barrier-free LDS exchange = UB (fixed: register exchange).
// R4: __shfl broadcast = ds_bpermute, 32 serialized LDS latencies
//     (fixed: __builtin_amdgcn_readlane -> SGPR, no LDS).
// R6 post-mortem: "gx_cur = gx_nxt" compiles to v_mov chain -> load must
// complete ONE iteration after issue (fake distance-2) -> ~1300 cyc/step
// memory stall. Fix: unroll-by-4 with 4 rotating load buffers; each substep
// consumes its buffer and reloads it for t+4 -> true distance-4, no movs.
// grid: 40 blocks x 64 threads.
// ---------------------------------------------------------------------------
__global__ void __launch_bounds__(64, 1) k_lstm(
    const float* __restrict__ gates_x, const float* __restrict__ W_hh,
    float* __restrict__ seq_out)
{
    const int b = blockIdx.x, j = threadIdx.x;

    // pack weight rows to half2: w?2[m] = (W?[j][2m], W?[j][2m+1])
    h2t wi2[32], wf2[32], wg2[32], wo2[32];
    const float* Wi = W_hh + (0 * 64 + j) * D_LSTM;
    const float* Wf = W_hh + (1 * 64 + j) * D_LSTM;
    const float* Wg = W_hh + (2 * 64 + j) * D_LSTM;
    const float* Wo = W_hh + (3 * 64 + j) * D_LSTM;
    #pragma unroll
    for (int m = 0; m < 32; ++m) {
        wi2[m] = (h2t){(_Float16)Wi[2 * m], (_Float16)Wi[2 * m + 1]};
        wf2[m] = (h2t){(_Float16)Wf[2 * m], (_Float16)Wf[2 * m + 1]};
        wg2[m] = (h2t){(_Float16)Wg[2 * m], (_Float16)Wg[2 * m + 1]};
        wo2[m] = (h2t){(_Float16)Wo[2 * m], (_Float16)Wo[2 * m + 1]};
    }

    const v4f* gxp = (const v4f*)(gates_x + (size_t)b * SEQ * G4);
    v4f g0 = gxp[0 * 64 + j];
    v4f g1 = gxp[1 * 64 + j];
    v4f g2 = gxp[2 * 64 + j];
    v4f g3 = gxp[3 * 64 + j];

    float h = 0.f, c = 0.f;
    float hpf = 0.f;   // packed (h[2m],h[2m+1]) as f16x2; lanes 2m,2m+1 hold pair m

    auto lstm_step = [&](v4f& gk, int t) {
        float ai = gk.x, af = gk.y, ag = gk.z, ao = gk.w;
        int tp = t + 4; if (tp > SEQ - 1) tp = SEQ - 1;
        gk = gxp[(size_t)tp * 64 + j];            // reload own buffer: distance-4

        const int hbits = __builtin_bit_cast(int, hpf);
        #pragma unroll
        for (int m = 0; m < 32; ++m) {
            // v_readlane_b32 -> SGPR: no LDS, 32 independent broadcasts
            int pmi = __builtin_amdgcn_readlane(hbits, 2 * m);
            h2t pm = __builtin_bit_cast(h2t, pmi);
            ai = __builtin_amdgcn_fdot2(wi2[m], pm, ai, false);
            af = __builtin_amdgcn_fdot2(wf2[m], pm, af, false);
            ag = __builtin_amdgcn_fdot2(wg2[m], pm, ag, false);
            ao = __builtin_amdgcn_fdot2(wo2[m], pm, ao, false);
        }

        c = sigmoid_f(af) * c + sigmoid_f(ai) * tanh_f(ag);
        h = sigmoid_f(ao) * tanh_f(c);
        seq_out[(size_t)(t * BATCH + b) * D_LSTM + j] = h;  // fire-and-forget

        // rebuild packed pair in-register: lanes 2m,2m+1 both hold pair m
        float hn = __shfl_xor(h, 1, 64);
        float lo = (j & 1) ? hn : h;
        float hi = (j & 1) ? h : hn;
        h2t hpk = {(_Float16)lo, (_Float16)hi};
        hpf = __builtin_bit_cast(float, hpk);
    };

    for (int t = 0; t < SEQ; t += 4) {
        lstm_step(g0, t + 0);
        lstm_step(g1, t + 1);
        lstm_step(g2, t + 2);
        lstm_step(g3, t + 3);
    }
}

// ---------------------------------------------------------------------------
// Kernel 3: multi-head attention, per (head, t). R5 post-mortem: projection
// paid 1 scalar-LDS read + 1 UNCOALESCED global weight read per FMA in the
// inner loop (64 cache lines per load instr) -> latency-bound, VALUBusy 11%.
// Fix (R6, verified): stage head W slices in LDS once per block (coalesced,
// L2-hot), register-block the projection: per k, 3 conflict-free sW reads
// (+1-pad stride 65) + 10 wave-uniform sA broadcasts feed 30 FMAs.
// LDS 78.5 KB -> 2 blocks/CU. grid: dim3(4, 640), 256 threads.
// ---------------------------------------------------------------------------
#define SQK 49   // padded row stride for q/k/v in LDS (break 48-stride conflicts)
#define SWS 65   // padded row stride for staged weights / seq rows
__global__ void __launch_bounds__(256) k_attn(
    const float* __restrict__ seq,
    const float* __restrict__ Wq, const float* __restrict__ bq,
    const float* __restrict__ Wk, const float* __restrict__ bk,
    const float* __restrict__ Wv, const float* __restrict__ bv,
    float* __restrict__ o_buf)
{
    const int h = blockIdx.x, t = blockIdx.y, tid = threadIdx.x;
    __shared__ float sW[144 * SWS];      // rows m*48+d (m in {q,k,v}), cols k
    __shared__ float sb[144];            // head bias slices
    __shared__ float sA[BATCH * SWS];    // seq_t rows
    __shared__ float sq[BATCH * SQK];
    __shared__ float sk[BATCH * SQK];
    __shared__ float sv[BATCH * SQK];
    __shared__ float ss[BATCH * 41];     // scores, padded

    // ---- stage head weight slices (coalesced: one wave covers one row) ----
    for (int i = tid; i < 144 * 64; i += 256) {
        int row = i >> 6, k = i & 63;
        int m = row / 48, d = row - m * 48;
        const float* W = (m == 0) ? Wq : (m == 1) ? Wk : Wv;
        sW[row * SWS + k] = W[(h * DH + d) * D_LSTM + k];
    }
    if (tid < 144) {
        int m = tid / 48, d = tid - m * 48;
        const float* B = (m == 0) ? bq : (m == 1) ? bk : bv;
        sb[tid] = B[h * DH + d];
    }
    for (int i = tid; i < BATCH * D_LSTM; i += 256)
        sA[(i >> 6) * SWS + (i & 63)] = seq[t * BATCH * D_LSTM + i];
    __syncthreads();

    // ---- q/k/v projection, register-blocked ----
    // lane -> cols {lane, lane+64, lane+128 (lanes<16)}; row-group rg -> 10 rows
    const int lane = tid & 63, rg = tid >> 6;
    const int b0 = rg * 10;
    const int c2row = (lane < 16) ? (lane + 128) : 0;   // clamped; acc2 unused if invalid
    float acc0[10], acc1[10], acc2[10];
    {
        float bias0 = sb[lane], bias1 = sb[lane + 64];
        float bias2 = (lane < 16) ? sb[lane + 128] : 0.f;
        #pragma unroll
        for (int r = 0; r < 10; ++r) { acc0[r] = bias0; acc1[r] = bias1; acc2[r] = bias2; }
    }
    #pragma unroll 4
    for (int k = 0; k < D_LSTM; ++k) {
        float w0 = sW[lane * SWS + k];
        float w1 = sW[(lane + 64) * SWS + k];
        float w2 = sW[c2row * SWS + k];
        float a[10];
        #pragma unroll
        for (int r = 0; r < 10; ++r) a[r] = sA[(b0 + r) * SWS + k];  // broadcast
        #pragma unroll
        for (int r = 0; r < 10; ++r) {
            acc0[r] += a[r] * w0;
            acc1[r] += a[r] * w1;
            acc2[r] += a[r] * w2;
        }
    }
    // write projection results into sq/sk/sv (padded)
    {
        int m0 = lane / 48, d0 = lane - m0 * 48;
        float* dst0 = (m0 == 0) ? sq : (m0 == 1) ? sk : sv;
        int c1 = lane + 64, m1 = c1 / 48, d1 = c1 - m1 * 48;
        float* dst1 = (m1 == 0) ? sq : (m1 == 1) ? sk : sv;
        #pragma unroll
        for (int r = 0; r < 10; ++r) {
            dst0[(b0 + r) * SQK + d0] = acc0[r];
            dst1[(b0 + r) * SQK + d1] = acc1[r];
        }
        if (lane < 16) {
            int c2 = lane + 128, d2 = c2 - 96;   // m2 == 2 -> v
            #pragma unroll
            for (int r = 0; r < 10; ++r) sv[(b0 + r) * SQK + d2] = acc2[r];
        }
    }
    __syncthreads();

    // ---- scores = q k^T / 8 ----
    for (int idx = tid; idx < BATCH * BATCH; idx += 256) {
        int i = idx / BATCH, j = idx % BATCH;
        float acc = 0.f;
        #pragma unroll 12
        for (int d = 0; d < DH; ++d) acc += sq[i * SQK + d] * sk[j * SQK + d];
        ss[i * 41 + j] = acc * 0.125f;
    }
    __syncthreads();

    // ---- row softmax (one thread per row) ----
    if (tid < BATCH) {
        float m = -1e30f;
        for (int j = 0; j < BATCH; ++j) m = fmaxf(m, ss[tid * 41 + j]);
        float s = 0.f;
        for (int j = 0; j < BATCH; ++j) {
            float e = __expf(ss[tid * 41 + j] - m);
            ss[tid * 41 + j] = e;
            s += e;
        }
        float inv = 1.f / s;
        for (int j = 0; j < BATCH; ++j) ss[tid * 41 + j] *= inv;
    }
    __syncthreads();

    // ---- o_h = a @ v ; write head slice into o_buf[t][b][h*48+d] ----
    for (int r = tid; r < BATCH * DH; r += 256) {
        int bi = r / DH, d = r % DH;
        float acc = 0.f;
        #pragma unroll 10
        for (int j = 0; j < BATCH; ++j) acc += ss[bi * 41 + j] * sv[j * SQK + d];
        o_buf[(t * BATCH + bi) * EMB + h * DH + d] = acc;
    }
}

// ---------------------------------------------------------------------------
// Kernel 4: GLU + residual + LayerNorm, per t. 256 threads.
// GLU phase: j = tid>>2 (output channel), bq = tid&3 (batch group of 10).
// LN phase: wave w handles rows {w, w+4, ...}; 64-lane shuffle reduction.
// ---------------------------------------------------------------------------
__global__ void __launch_bounds__(256) k_glu_ln(
    const float* __restrict__ seq, const float* __restrict__ obuf,
    const float* __restrict__ Wa, const float* __restrict__ ba,
    const float* __restrict__ Wg, const float* __restrict__ bg,
    const float* __restrict__ gamma, const float* __restrict__ beta,
    float* __restrict__ out)
{
    const int t = blockIdx.x, tid = threadIdx.x;
    __shared__ float so[BATCH * 193];       // o_t padded (192 -> 193)
    __shared__ float sy[BATCH * 65];        // y padded
    __shared__ float sseq[BATCH * D_LSTM];

    const float* ot = obuf + t * BATCH * EMB;
    for (int i = tid; i < BATCH * EMB; i += 256)
        so[(i / EMB) * 193 + (i % EMB)] = ot[i];
    for (int i = tid; i < BATCH * D_LSTM; i += 256)
        sseq[i] = seq[t * BATCH * D_LSTM + i];
    __syncthreads();

    const int j = tid >> 2, bgr = tid & 3;
    float acc_a[10], acc_g[10];
    #pragma unroll
    for (int bb = 0; bb < 10; ++bb) { acc_a[bb] = ba[j]; acc_g[bb] = bg[j]; }

    const float* wa = Wa + j * EMB;
    const float* wg = Wg + j * EMB;
    for (int p = 0; p < EMB; ++p) {
        float a = wa[p], g = wg[p];
        #pragma unroll
        for (int bb = 0; bb < 10; ++bb) {
            float o = so[(bgr + 4 * bb) * 193 + p];
            acc_a[bb] += o * a;
            acc_g[bb] += o * g;
        }
    }
    #pragma unroll
    for (int bb = 0; bb < 10; ++bb) {
        int b = bgr + 4 * bb;
        float tv = acc_a[bb] * sigmoid_f(acc_g[bb]);
        sy[b * 65 + j] = sseq[b * D_LSTM + j] + tv;
    }
    __syncthreads();

    const int w = tid >> 6, lane = tid & 63;
    const float gm = gamma[lane], bt = beta[lane];
    for (int rr = 0; rr < 10; ++rr) {
        int b = w + 4 * rr;
        float y = sy[b * 65 + lane];
        float s1 = y, s2 = y * y;
        #pragma unroll
        for (int m = 1; m < 64; m <<= 1) {
            s1 += __shfl_xor(s1, m, 64);
            s2 += __shfl_xor(s2, m, 64);
        }
        float mu  = s1 * (1.f / 64.f);
        float var = s2 * (1.f / 64.f) - mu * mu;
        float inv = rsqrtf(var + 1e-5f);
        out[t * BATCH * D_LSTM + b * D_LSTM + lane] = (y - mu) * inv * gm + bt;
    }
}

// ---------------------------------------------------------------------------
extern "C" void kernel_launch(void* const* d_in, const int* in_sizes, int n_in,
                              void* d_out, int out_size, void* d_ws, size_t ws_size,
                              hipStream_t stream)
{
    const float* hist = (const float*)d_in[0];
    // d_in[1] adj: unused (use_spatial=False)
    const float* W1   = (const float*)d_in[2];
    const float* b1   = (const float*)d_in[3];
    const float* W_ih = (const float*)d_in[4];
    const float* W_hh = (const float*)d_in[5];
    const float* b_ih = (const float*)d_in[6];
    const float* b_hh = (const float*)d_in[7];
    const float* Wq   = (const float*)d_in[8];
    const float* bq   = (const float*)d_in[9];
    const float* Wk   = (const float*)d_in[10];
    const float* bk   = (const float*)d_in[11];
    const float* Wv   = (const float*)d_in[12];
    const float* bv   = (const float*)d_in[13];
    const float* Wa   = (const float*)d_in[14];
    const float* ba   = (const float*)d_in[15];
    const float* Wg   = (const float*)d_in[16];
    const float* bg   = (const float*)d_in[17];
    const float* gamma = (const float*)d_in[18];
    const float* beta  = (const float*)d_in[19];
    float* out = (float*)d_out;

    float* ws = (float*)d_ws;
    float* gates_x = ws;                                   // 640*40*256 = 6,553,600 f
    float* seq     = ws + 6553600;                         // 640*40*64  = 1,638,400 f
    float* obuf    = ws + 6553600 + 1638400;               // 640*40*192 = 4,915,200 f

    hipLaunchKernelGGL(k_embed, dim3(SEQ), dim3(256), 0, stream,
                       hist, W1, b1, W_ih, b_ih, b_hh, gates_x);
    hipLaunchKernelGGL(k_lstm, dim3(BATCH), dim3(64), 0, stream,
                       gates_x, W_hh, seq);
    hipLaunchKernelGGL(k_attn, dim3(NH, SEQ), dim3(256), 0, stream,
                       seq, Wq, bq, Wk, bk, Wv, bv, obuf);
    hipLaunchKernelGGL(k_glu_ln, dim3(SEQ), dim3(256), 0, stream,
                       seq, obuf, Wa, ba, Wg, bg, gamma, beta, out);
}